// Round 1
// 290.064 us; speedup vs baseline: 1.3348x; 1.3348x over previous
//
#include <hip/hip_runtime.h>

// Problem constants (match reference)
#define C 80
#define P 30000
#define G 800
#define BS 256
#define NB 16         // 64-px cells over [0,1024); boxes binned by CENTER
#define NC (NB * NB)  // 256 cells per class
#define HCH 8         // hist chunks per class
#define CHSZ ((P + HCH - 1) / HCH)   // 3750

// Center-binning prune: IoU <= iw/aw, iw/bw, ih/ah, ih/bh. IoU > 0.5 forces
// each ratio > 1/2, which forces each box to contain the other's center in
// both dims, hence |c_a - c_b| < min(w_a,w_b)/2 <= 64 px per dim. With 64-px
// center cells, every pair that can possibly be valid lies in the 3x3
// neighborhood of the pred's center cell. Pruned pairs provably have
// IoU <= 0.5, so the kept-set argmax equals the global argmax whenever the
// global best IoU > 0.5; validity is re-verified with the bit-exact
// reference division in the epilogue. Candidates/pred: ~120 -> ~30.

// rank order = score desc, then pred-index asc. Packed key is monotone in that
// order (scores >= 0 so float bits are order-preserving). key==0 means "no
// match" (needs score==0.0f AND p==P-1 — probability ~0).
__device__ __forceinline__ unsigned long long pack_key(float s, int p) {
    return ((unsigned long long)__float_as_uint(s) << 32) | (unsigned)(P - 1 - p);
}

// cell of a box by its CENTER (cx, cy)
__device__ __forceinline__ int cell_of(float cx, float cy) {
    int bx = (int)(cx * (1.0f / 64.0f));
    int by = (int)(cy * (1.0f / 64.0f));
    bx = min(max(bx, 0), NB - 1);
    by = min(max(by, 0), NB - 1);
    return by * NB + bx;
}

// ---------------- init: zero everything read-before-write ----------------
__global__ void init_kernel(unsigned long long* __restrict__ gtKey,
                            int* __restrict__ predCnt,
                            int* __restrict__ gHist) {
    int idx = blockIdx.x * blockDim.x + threadIdx.x;
    if (idx < C * G) gtKey[idx] = 0ull;
    if (idx < C * NC) predCnt[idx] = 0;
    if (idx < C * 1024) gHist[idx] = 0;
}

// ---------------- gt binning: one block per class (count+scan+scatter) ------
// BS == NC == 256: thread t owns cell t for the histogram + LDS Hillis-Steele
// exclusive scan.
__global__ __launch_bounds__(BS) void gt_bin_kernel(
        const float* __restrict__ gt,
        unsigned short* __restrict__ gtCnt, unsigned short* __restrict__ gtOff,
        float4* __restrict__ gtBox, float* __restrict__ gtAbe,
        unsigned short* __restrict__ gtIdx) {
    __shared__ int h[NC], cur[NC];
    __shared__ int gcell[G];
    const int c = blockIdx.x, tid = threadIdx.x;
    h[tid] = 0;
    __syncthreads();
    for (int i = tid; i < G; i += BS) {
        const float* r = gt + ((size_t)c * G + i) * 7;
        int cl = cell_of(0.5f * (r[3] + r[5]), 0.5f * (r[4] + r[6]));
        gcell[i] = cl;
        atomicAdd(&h[cl], 1);
    }
    __syncthreads();
    const int v = h[tid];
    cur[tid] = v;
    __syncthreads();
    for (int o = 1; o < NC; o <<= 1) {   // inclusive scan, 8 steps
        int t = (tid >= o) ? cur[tid - o] : 0;
        __syncthreads();
        cur[tid] += t;
        __syncthreads();
    }
    const int excl = cur[tid] - v;
    gtOff[c * NC + tid] = (unsigned short)excl;
    gtCnt[c * NC + tid] = (unsigned short)v;
    __syncthreads();
    cur[tid] = excl;
    __syncthreads();
    for (int i = tid; i < G; i += BS) {
        const float* r = gt + ((size_t)c * G + i) * 7;   // L1-hot (2nd pass)
        float x1 = r[3], y1 = r[4], x2 = r[5], y2 = r[6];
        int slot = atomicAdd(&cur[gcell[i]], 1);
        gtBox[c * G + slot] = make_float4(x1, y1, x2, y2);
        // area + eps pre-folded: cross-compare uses sb = A + (area_g + eps);
        // the -inter terms of the two denominators cancel algebraically.
        gtAbe[c * G + slot] = __fadd_rn(__fmul_rn(__fsub_rn(x2, x1), __fsub_rn(y2, y1)), 1e-9f);
        gtIdx[c * G + slot] = (unsigned short)i;
    }
}

// ---------------- pred prep: count hist + score extraction + cell cache ------
__global__ __launch_bounds__(BS) void pred_prep_kernel(
        const float* __restrict__ pred, int* __restrict__ predCnt,
        float* __restrict__ scoreC, unsigned char* __restrict__ cellB) {
    __shared__ int h[NC];
    const int c = blockIdx.y, tid = threadIdx.x;
    h[tid] = 0;
    __syncthreads();
    int p = blockIdx.x * BS + tid;
    if (p < P) {
        const float* r = pred + ((size_t)c * P + p) * 7;
        scoreC[(size_t)c * P + p] = r[2];
        int cl = cell_of(0.5f * (r[3] + r[5]), 0.5f * (r[4] + r[6]));
        cellB[(size_t)c * P + p] = (unsigned char)cl;   // NC==256 fits uchar
        atomicAdd(&h[cl], 1);
    }
    __syncthreads();
    if (h[tid]) atomicAdd(&predCnt[c * NC + tid], h[tid]);   // no-return
}

// ---------------- pred scan: one 256-thread block per class ----------------
__global__ __launch_bounds__(NC) void pred_scan_kernel(
        const int* __restrict__ predCnt,
        unsigned short* __restrict__ predOff, int* __restrict__ predCur) {
    __shared__ int sc[NC];
    const int c = blockIdx.x, tid = threadIdx.x;
    const int v = predCnt[c * NC + tid];
    sc[tid] = v;
    __syncthreads();
    for (int o = 1; o < NC; o <<= 1) {
        int t = (tid >= o) ? sc[tid - o] : 0;
        __syncthreads();
        sc[tid] += t;
        __syncthreads();
    }
    const int excl = sc[tid] - v;
    predOff[c * NC + tid] = (unsigned short)excl;   // offsets < P < 65536
    predCur[c * NC + tid] = excl;
}

// ---------------- pred scatter: cellB-only read, LDS-aggregated slots -------
__global__ __launch_bounds__(BS) void pred_scatter_kernel(
        const unsigned char* __restrict__ cellB, int* __restrict__ predCur,
        int* __restrict__ predP) {
    __shared__ int h[NC], base[NC];
    const int c = blockIdx.y, tid = threadIdx.x;
    h[tid] = 0;
    __syncthreads();
    int p = blockIdx.x * BS + tid;
    int cellv = 0, lr = 0;
    if (p < P) {
        cellv = cellB[(size_t)c * P + p];
        lr = atomicAdd(&h[cellv], 1);   // LDS, local rank
    }
    __syncthreads();
    if (h[tid]) base[tid] = atomicAdd(&predCur[c * NC + tid], h[tid]);
    __syncthreads();
    if (p < P) predP[(size_t)c * P + base[cellv] + lr] = p;
}

// ---------------- match: block per (center-cell, class) ----------------
// 3x3 GT center-cell neighborhood staged in LDS (~30 candidates). Argmax via
// cancelled cross-multiply: iou_g > iou_best <=> inter_g*sb_best >
// inter_best*sb_g, sb = A + area + eps. Epilogue recomputes the
// reference-order denominator exactly for the selected pair, so the >0.5
// validity test uses the bit-exact reference iou.
__global__ __launch_bounds__(BS) void match2_kernel(
        const float* __restrict__ pred,
        const unsigned short* __restrict__ gtOff, const unsigned short* __restrict__ gtCnt,
        const float4* __restrict__ gtBox, const float* __restrict__ gtAbe,
        const unsigned short* __restrict__ gtIdx,
        const unsigned short* __restrict__ predOff, const int* __restrict__ predCnt,
        const int* __restrict__ predP,
        unsigned long long* __restrict__ gtKey) {
    __shared__ float4 sB[G];
    __shared__ float  sE[G];
    __shared__ int    sG[G];
    const int c = blockIdx.y, cell = blockIdx.x;
    const int tid = threadIdx.x;

    const int pCnt = predCnt[c * NC + cell];
    if (pCnt == 0) return;   // block-uniform early exit
    const int pOff = predOff[c * NC + cell];

    const int cx = cell & (NB - 1), cy = cell >> 4;
    int total = 0;
    for (int dy = -1; dy <= 1; ++dy) {
        int yy = cy + dy; if (yy < 0 || yy >= NB) continue;
        for (int dx = -1; dx <= 1; ++dx) {
            int xx = cx + dx; if (xx < 0 || xx >= NB) continue;
            int nc = yy * NB + xx;
            int off = gtOff[c * NC + nc], cnt = gtCnt[c * NC + nc];
            for (int i = tid; i < cnt; i += BS) {
                sB[total + i] = gtBox[c * G + off + i];
                sE[total + i] = gtAbe[c * G + off + i];
                sG[total + i] = gtIdx[c * G + off + i];
            }
            total += cnt;   // uniform across threads
        }
    }
    if (total == 0) return;   // uniform: no GT can match these preds
    __syncthreads();

    for (int i = tid; i < pCnt; i += BS) {
        int p = predP[(size_t)c * P + pOff + i];
        const float* r = pred + ((size_t)c * P + p) * 7;
        float ax1 = r[3], ay1 = r[4], ax2 = r[5], ay2 = r[6];
        float A   = __fmul_rn(__fsub_rn(ax2, ax1), __fsub_rn(ay2, ay1));
        float IN = 0.0f, SB = 1.0f;
        int mj = -1;
        #pragma unroll 4
        for (int j = 0; j < total; ++j) {
            float4 b = sB[j];
            float lx = fmaxf(ax1, b.x), ly = fmaxf(ay1, b.y);
            float rx = fminf(ax2, b.z), ry = fminf(ay2, b.w);
            float wx = fmaxf(__fsub_rn(rx, lx), 0.0f);
            float wy = fmaxf(__fsub_rn(ry, ly), 0.0f);
            float in = __fmul_rn(wx, wy);
            float sb = __fadd_rn(A, sE[j]);
            bool  up = __fmul_rn(in, SB) > __fmul_rn(IN, sb);
            IN = up ? in : IN; SB = up ? sb : SB; mj = up ? j : mj;
        }
        if (IN > 0.0f) {   // zero-inter preds can never be valid
            float4 b = sB[mj];
            float area = __fmul_rn(__fsub_rn(b.z, b.x), __fsub_rn(b.w, b.y));
            float dn = __fadd_rn(__fsub_rn(__fadd_rn(A, area), IN), 1e-9f);
            float iou = __fdiv_rn(IN, dn);   // exact reference value for this pair
            if (iou > 0.5f) {
                float s = r[2];              // rare path: load score only here
                atomicMax(&gtKey[c * G + sG[mj]], pack_key(s, p));
            }
        }
    }
}

// ---------------- sortc: compact gtKey + position-sort, one block/class -----
__global__ __launch_bounds__(BS) void sortc_kernel(
        const unsigned long long* __restrict__ gtKey,
        unsigned long long* __restrict__ sortedKeys, int* __restrict__ sortT) {
    __shared__ unsigned long long k[G];
    __shared__ unsigned long long sk[1024];
    __shared__ int cnt;
    const int c = blockIdx.x, tid = threadIdx.x;
    if (tid == 0) cnt = 0;
    for (int j = tid; j < 1024; j += BS) sk[j] = 0ull;
    __syncthreads();
    for (int i = tid; i < G; i += BS) {
        unsigned long long key = gtKey[c * G + i];
        if (key != 0ull) k[atomicAdd(&cnt, 1)] = key;
    }
    __syncthreads();
    const int T = cnt;
    if (tid == 0) sortT[c] = T;
    for (int t = tid; t < T; t += BS) {
        unsigned long long key = k[t];
        int pos = 0;
        for (int u = 0; u < T; ++u) pos += (k[u] > key) ? 1 : 0;   // keys unique
        sk[pos] = key;
    }
    __syncthreads();
    for (int j = tid; j < 1024; j += BS) sortedKeys[c * 1024 + j] = sk[j];
}

// ---------------- hist: pos(q) for every pred via binary search ----------
__global__ __launch_bounds__(BS) void hist_kernel(
        const float* __restrict__ scoreC,
        const unsigned long long* __restrict__ sortedKeys,
        int* __restrict__ gHist) {
    __shared__ unsigned long long sK[1024];
    __shared__ int h[1024];
    const int c = blockIdx.y, tid = threadIdx.x;
    for (int j = tid; j < 1024; j += BS) { sK[j] = sortedKeys[c * 1024 + j]; h[j] = 0; }
    __syncthreads();
    const int start = blockIdx.x * CHSZ;
    const int end   = min(start + CHSZ, P);
    const float* sc = scoreC + (size_t)c * P;
    for (int i = start + tid; i < end; i += BS) {
        unsigned long long kq =
            ((unsigned long long)__float_as_uint(sc[i]) << 32) | (unsigned)(P - 1 - i);
        int lo = 0;   // count of sorted-desc keys > kq (pads are 0, never > kq)
        #pragma unroll
        for (int step = 512; step > 0; step >>= 1)
            if (sK[lo + step - 1] > kq) lo += step;
        atomicAdd(&h[lo], 1);
    }
    __syncthreads();
    for (int j = tid; j < 1024; j += BS)
        if (h[j]) atomicAdd(&gHist[c * 1024 + j], h[j]);   // no-return
}

// ---------------- ap: prefix over hist + closed-form terms ----------------
__global__ __launch_bounds__(BS) void ap2_kernel(
        const int* __restrict__ sortT, const int* __restrict__ gHist,
        float* __restrict__ ap) {
    __shared__ int ha[1024];
    __shared__ int hb[1024];
    __shared__ float red[BS];
    const int c = blockIdx.x, tid = threadIdx.x;
    const int T = sortT[c];
    for (int j = tid; j < 1024; j += BS) ha[j] = gHist[c * 1024 + j];
    __syncthreads();
    int* src = ha; int* dst = hb;
    for (int o = 1; o < 1024; o <<= 1) {
        for (int j = tid; j < 1024; j += BS)
            dst[j] = src[j] + ((j >= o) ? src[j - o] : 0);
        __syncthreads();
        int* tmp = src; src = dst; dst = tmp;
    }
    float sum = 0.0f;
    for (int s = tid; s < T; s += BS) {
        int r = src[s] - 1;          // inclusive prefix minus self
        if (r >= 1) {
            float kf  = (float)(s + 1);
            float km  = (float)s;
            float ri  = __fdiv_rn(kf, 800.0f);
            float rim = __fdiv_rn(km, 800.0f);
            float pi  = __fdiv_rn(kf, (float)(r + 1));
            float pim = __fdiv_rn(km, (float)r);
            sum = __fadd_rn(sum,
                  __fmul_rn(__fmul_rn(__fsub_rn(ri, rim), __fadd_rn(pi, pim)), 0.5f));
        }
    }
    red[tid] = sum;
    __syncthreads();
    for (int s2 = BS / 2; s2 > 0; s2 >>= 1) {
        if (tid < s2) red[tid] = __fadd_rn(red[tid], red[tid + s2]);
        __syncthreads();
    }
    if (tid == 0) ap[c] = red[0];
}

// ---------------- mean over classes ----------------
__global__ void mean_kernel(const float* __restrict__ ap, float* __restrict__ out) {
    if (threadIdx.x == 0) {
        float s = 0.0f;
        for (int c = 0; c < C; ++c) s = __fadd_rn(s, ap[c]);
        out[0] = __fdiv_rn(s, 80.0f);
    }
}

extern "C" void kernel_launch(void* const* d_in, const int* in_sizes, int n_in,
                              void* d_out, int out_size, void* d_ws, size_t ws_size,
                              hipStream_t stream) {
    const float* pred = (const float*)d_in[0];   // [C, P, 7] f32
    const float* gt   = (const float*)d_in[1];   // [C, G, 7] f32
    float* out = (float*)d_out;

    // Workspace layout — 24,708,864 B total, kept UNDER the previously proven
    // 24,734,464 B footprint despite NC 64->256 by (a) ushort metadata
    // (counts/offsets < 65536), (b) aliasing predCur over sortedKeys:
    // predCur's last use is pred_scatter; sortc later rewrites every element
    // of sortedKeys before hist/ap read it. Re-poisoned 0xAA each call —
    // init/gt_bin/pred_scan/sortc rewrite everything read-before-write.
    char* ws = (char*)d_ws;
    int*                sortT      = (int*)               (ws + 0);         //    320 B
    float*              ap         = (float*)             (ws + 512);       //    320 B
    int*                predCnt    = (int*)               (ws + 1024);      //  81920 B
    unsigned short*     gtIdx      = (unsigned short*)    (ws + 82944);     // 128000 B
    unsigned short*     predOff    = (unsigned short*)    (ws + 210944);    //  40960 B
    unsigned short*     gtCnt      = (unsigned short*)    (ws + 251904);    //  40960 B
    unsigned short*     gtOff      = (unsigned short*)    (ws + 292864);    //  40960 B
    float*              gtAbe      = (float*)             (ws + 333824);    // 256000 B
    float4*             gtBox      = (float4*)            (ws + 589824);    // 1.024 MB (16-aligned)
    unsigned long long* gtKey      = (unsigned long long*)(ws + 1613824);   // 512000 B
    unsigned long long* sortedKeys = (unsigned long long*)(ws + 2125824);   // 655360 B
    int*                predCur    = (int*)               (ws + 2125824);   // ALIAS over sortedKeys
    int*                gHist      = (int*)               (ws + 2781184);   // 327680 B
    unsigned char*      cellB      = (unsigned char*)     (ws + 3108864);   // 2.4 MB
    int*                predP      = (int*)               (ws + 5508864);   // 9.6 MB
    float*              scoreC     = (float*)             (ws + 15108864);  // 9.6 MB
    // end: 24708864 B

    const int P_BLK = (P + BS - 1) / BS;   // 118

    init_kernel<<<(C * 1024 + BS - 1) / BS, BS, 0, stream>>>(gtKey, predCnt, gHist);
    gt_bin_kernel<<<C, BS, 0, stream>>>(gt, gtCnt, gtOff, gtBox, gtAbe, gtIdx);
    pred_prep_kernel<<<dim3(P_BLK, C), BS, 0, stream>>>(pred, predCnt, scoreC, cellB);
    pred_scan_kernel<<<C, NC, 0, stream>>>(predCnt, predOff, predCur);
    pred_scatter_kernel<<<dim3(P_BLK, C), BS, 0, stream>>>(cellB, predCur, predP);
    match2_kernel<<<dim3(NC, C), BS, 0, stream>>>(pred, gtOff, gtCnt, gtBox, gtAbe, gtIdx,
                                                  predOff, predCnt, predP, gtKey);
    sortc_kernel<<<C, BS, 0, stream>>>(gtKey, sortedKeys, sortT);
    hist_kernel<<<dim3(HCH, C), BS, 0, stream>>>(scoreC, sortedKeys, gHist);
    ap2_kernel<<<C, BS, 0, stream>>>(sortT, gHist, ap);
    mean_kernel<<<1, 64, 0, stream>>>(ap, out);
}

// Round 2
// 243.237 us; speedup vs baseline: 1.5918x; 1.1925x over previous
//
#include <hip/hip_runtime.h>

// Problem constants (match reference)
#define C 80
#define P 30000
#define G 800
#define BS 256
#define NB 16         // 64-px cells over [0,1024); boxes binned by CENTER
#define NC (NB * NB)  // 256 cells per class
#define PPT 2         // preds per thread in match (halves GT-staging traffic)
#define HCH 8         // hist chunks per class
#define CHSZ ((P + HCH - 1) / HCH)   // 3750

// Center-binning prune: IoU <= iw/aw, iw/bw, ih/ah, ih/bh. IoU > 0.5 forces
// each ratio > 1/2, which forces each box to contain the other's center in
// both dims, hence |c_a - c_b| < min(w_a,w_b)/2 <= 64 px per dim. With 64-px
// center cells, every pair that can possibly be valid lies in the 3x3
// neighborhood of the pred's center cell. Pruned pairs provably have
// IoU <= 0.5, so the kept-set argmax equals the global argmax whenever the
// global best IoU > 0.5; validity is re-verified with the bit-exact
// reference division in the epilogue. (Validated: absmax 0.0 in round 1.)

// rank order = score desc, then pred-index asc. Packed key is monotone in that
// order (scores >= 0 so float bits are order-preserving). key==0 means "no
// match" (needs score==0.0f AND p==P-1 — probability ~0).
__device__ __forceinline__ unsigned long long pack_key(float s, int p) {
    return ((unsigned long long)__float_as_uint(s) << 32) | (unsigned)(P - 1 - p);
}

// ---------------- gt binning: one block per class (count+scan+scatter) ------
// BS == NC == 256: thread t owns cell t for the histogram + LDS Hillis-Steele
// scan. Also zeroes this class's gtKey + gHist (init kernel folded in).
__global__ __launch_bounds__(BS) void gt_bin_kernel(
        const float* __restrict__ gt,
        unsigned short* __restrict__ gtCnt, unsigned short* __restrict__ gtOff,
        float4* __restrict__ gtBox, float* __restrict__ gtAbe,
        unsigned short* __restrict__ gtIdx,
        unsigned long long* __restrict__ gtKey, int* __restrict__ gHist) {
    __shared__ int h[NC], cur[NC];
    __shared__ int gcell[G];
    const int c = blockIdx.x, tid = threadIdx.x;
    h[tid] = 0;
    for (int i = tid; i < G; i += BS) gtKey[c * G + i] = 0ull;       // folded init
    for (int j = tid; j < 1024; j += BS) gHist[c * 1024 + j] = 0;    // folded init
    __syncthreads();
    for (int i = tid; i < G; i += BS) {
        const float* r = gt + ((size_t)c * G + i) * 7;
        float cxf = 0.5f * (r[3] + r[5]), cyf = 0.5f * (r[4] + r[6]);
        int bx = min(max((int)(cxf * (1.0f / 64.0f)), 0), NB - 1);
        int by = min(max((int)(cyf * (1.0f / 64.0f)), 0), NB - 1);
        int cl = by * NB + bx;
        gcell[i] = cl;
        atomicAdd(&h[cl], 1);
    }
    __syncthreads();
    const int v = h[tid];
    cur[tid] = v;
    __syncthreads();
    for (int o = 1; o < NC; o <<= 1) {   // inclusive scan, 8 steps
        int t = (tid >= o) ? cur[tid - o] : 0;
        __syncthreads();
        cur[tid] += t;
        __syncthreads();
    }
    const int excl = cur[tid] - v;
    gtOff[c * NC + tid] = (unsigned short)excl;
    gtCnt[c * NC + tid] = (unsigned short)v;
    __syncthreads();
    cur[tid] = excl;
    __syncthreads();
    for (int i = tid; i < G; i += BS) {
        const float* r = gt + ((size_t)c * G + i) * 7;   // L1-hot (2nd pass)
        float x1 = r[3], y1 = r[4], x2 = r[5], y2 = r[6];
        int slot = atomicAdd(&cur[gcell[i]], 1);
        gtBox[c * G + slot] = make_float4(x1, y1, x2, y2);
        // area + eps pre-folded: cross-compare uses sb = A + (area_g + eps);
        // the -inter terms of the two denominators cancel algebraically.
        gtAbe[c * G + slot] = __fadd_rn(__fmul_rn(__fsub_rn(x2, x1), __fsub_rn(y2, y1)), 1e-9f);
        gtIdx[c * G + slot] = (unsigned short)i;
    }
}

// ---------------- match: stream preds coalesced, whole-class GT in LDS ------
// One block covers PPT*BS consecutive preds of one class. The ENTIRE class GT
// (800 boxes, cell-sorted) is staged in LDS as SoA (18.6 KB -> 8 blocks/CU by
// LDS). Each thread reads its pred row in original order (fully coalesced),
// computes its center cell, and scans the 3x3 neighborhood as THREE CONTIGUOUS
// LDS ranges (cells of one row are adjacent in the cell-sorted layout:
// range = [off[y][x0], off[y][x1]+cnt[y][x1]) ). SoA f32 keeps divergent
// per-lane LDS reads at ~2-way bank aliasing (free) instead of b128 8-way.
// Argmax via cancelled cross-multiply: iou_g > iou_best <=> inter_g*sb_best >
// inter_best*sb_g, sb = A + area + eps. Epilogue recomputes the
// reference-order denominator exactly for the selected pair, so the >0.5
// validity test uses the bit-exact reference iou. Also writes scoreC (the
// row is already in registers), replacing the old pred_prep pass.
__global__ __launch_bounds__(BS) void match3_kernel(
        const float* __restrict__ pred,
        const unsigned short* __restrict__ gtOff, const unsigned short* __restrict__ gtCnt,
        const float4* __restrict__ gtBox, const float* __restrict__ gtAbe,
        const unsigned short* __restrict__ gtIdx,
        float* __restrict__ scoreC,
        unsigned long long* __restrict__ gtKey) {
    __shared__ float sX1[G], sY1[G], sX2[G], sY2[G], sE[G];
    __shared__ unsigned short sG[G];
    __shared__ unsigned short sOff[NC], sCnt[NC];
    const int c = blockIdx.y, tid = threadIdx.x;

    for (int i = tid; i < G; i += BS) {
        float4 b = gtBox[c * G + i];
        sX1[i] = b.x; sY1[i] = b.y; sX2[i] = b.z; sY2[i] = b.w;
        sE[i] = gtAbe[c * G + i];
        sG[i] = gtIdx[c * G + i];
    }
    sOff[tid] = gtOff[c * NC + tid];   // BS == NC
    sCnt[tid] = gtCnt[c * NC + tid];
    __syncthreads();

    const size_t cp = (size_t)c * P;
    #pragma unroll
    for (int rep = 0; rep < PPT; ++rep) {
        const int p = (blockIdx.x * PPT + rep) * BS + tid;
        if (p < P) {
            const float* r = pred + (cp + p) * 7;
            float s   = r[2];
            float ax1 = r[3], ay1 = r[4], ax2 = r[5], ay2 = r[6];
            scoreC[cp + p] = s;
            float A = __fmul_rn(__fsub_rn(ax2, ax1), __fsub_rn(ay2, ay1));
            float cxf = 0.5f * (ax1 + ax2), cyf = 0.5f * (ay1 + ay2);
            int cx = min(max((int)(cxf * (1.0f / 64.0f)), 0), NB - 1);
            int cy = min(max((int)(cyf * (1.0f / 64.0f)), 0), NB - 1);
            int x0 = max(cx - 1, 0), x1 = min(cx + 1, NB - 1);
            int y0 = max(cy - 1, 0), y1 = min(cy + 1, NB - 1);
            float IN = 0.0f, SB = 1.0f;
            int mj = -1;
            for (int yy = y0; yy <= y1; ++yy) {
                const int rowb = yy * NB;
                const int jb = sOff[rowb + x0];
                const int je = sOff[rowb + x1] + sCnt[rowb + x1];
                for (int j = jb; j < je; ++j) {
                    float bx1 = sX1[j], by1 = sY1[j];
                    float bx2 = sX2[j], by2 = sY2[j];
                    float lx = fmaxf(ax1, bx1), ly = fmaxf(ay1, by1);
                    float rx = fminf(ax2, bx2), ry = fminf(ay2, by2);
                    float wx = fmaxf(__fsub_rn(rx, lx), 0.0f);
                    float wy = fmaxf(__fsub_rn(ry, ly), 0.0f);
                    float in = __fmul_rn(wx, wy);
                    float sb = __fadd_rn(A, sE[j]);
                    bool  up = __fmul_rn(in, SB) > __fmul_rn(IN, sb);
                    IN = up ? in : IN; SB = up ? sb : SB; mj = up ? j : mj;
                }
            }
            if (IN > 0.0f) {   // zero-inter preds can never be valid
                float bx1 = sX1[mj], by1 = sY1[mj], bx2 = sX2[mj], by2 = sY2[mj];
                float area = __fmul_rn(__fsub_rn(bx2, bx1), __fsub_rn(by2, by1));
                float dn = __fadd_rn(__fsub_rn(__fadd_rn(A, area), IN), 1e-9f);
                float iou = __fdiv_rn(IN, dn);   // exact reference value
                if (iou > 0.5f)
                    atomicMax(&gtKey[c * G + sG[mj]], pack_key(s, p));
            }
        }
    }
}

// ---------------- sortc: compact gtKey + position-sort, one block/class -----
__global__ __launch_bounds__(BS) void sortc_kernel(
        const unsigned long long* __restrict__ gtKey,
        unsigned long long* __restrict__ sortedKeys, int* __restrict__ sortT) {
    __shared__ unsigned long long k[G];
    __shared__ unsigned long long sk[1024];
    __shared__ int cnt;
    const int c = blockIdx.x, tid = threadIdx.x;
    if (tid == 0) cnt = 0;
    for (int j = tid; j < 1024; j += BS) sk[j] = 0ull;
    __syncthreads();
    for (int i = tid; i < G; i += BS) {
        unsigned long long key = gtKey[c * G + i];
        if (key != 0ull) k[atomicAdd(&cnt, 1)] = key;
    }
    __syncthreads();
    const int T = cnt;
    if (tid == 0) sortT[c] = T;
    for (int t = tid; t < T; t += BS) {
        unsigned long long key = k[t];
        int pos = 0;
        for (int u = 0; u < T; ++u) pos += (k[u] > key) ? 1 : 0;   // keys unique
        sk[pos] = key;
    }
    __syncthreads();
    for (int j = tid; j < 1024; j += BS) sortedKeys[c * 1024 + j] = sk[j];
}

// ---------------- hist: pos(q) for every pred via binary search ----------
__global__ __launch_bounds__(BS) void hist_kernel(
        const float* __restrict__ scoreC,
        const unsigned long long* __restrict__ sortedKeys,
        int* __restrict__ gHist) {
    __shared__ unsigned long long sK[1024];
    __shared__ int h[1024];
    const int c = blockIdx.y, tid = threadIdx.x;
    for (int j = tid; j < 1024; j += BS) { sK[j] = sortedKeys[c * 1024 + j]; h[j] = 0; }
    __syncthreads();
    const int start = blockIdx.x * CHSZ;
    const int end   = min(start + CHSZ, P);
    const float* sc = scoreC + (size_t)c * P;
    for (int i = start + tid; i < end; i += BS) {
        unsigned long long kq =
            ((unsigned long long)__float_as_uint(sc[i]) << 32) | (unsigned)(P - 1 - i);
        int lo = 0;   // count of sorted-desc keys > kq (pads are 0, never > kq)
        #pragma unroll
        for (int step = 512; step > 0; step >>= 1)
            if (sK[lo + step - 1] > kq) lo += step;
        atomicAdd(&h[lo], 1);
    }
    __syncthreads();
    for (int j = tid; j < 1024; j += BS)
        if (h[j]) atomicAdd(&gHist[c * 1024 + j], h[j]);   // no-return
}

// ---------------- ap: prefix over hist + closed-form terms ----------------
__global__ __launch_bounds__(BS) void ap2_kernel(
        const int* __restrict__ sortT, const int* __restrict__ gHist,
        float* __restrict__ ap) {
    __shared__ int ha[1024];
    __shared__ int hb[1024];
    __shared__ float red[BS];
    const int c = blockIdx.x, tid = threadIdx.x;
    const int T = sortT[c];
    for (int j = tid; j < 1024; j += BS) ha[j] = gHist[c * 1024 + j];
    __syncthreads();
    int* src = ha; int* dst = hb;
    for (int o = 1; o < 1024; o <<= 1) {
        for (int j = tid; j < 1024; j += BS)
            dst[j] = src[j] + ((j >= o) ? src[j - o] : 0);
        __syncthreads();
        int* tmp = src; src = dst; dst = tmp;
    }
    float sum = 0.0f;
    for (int s = tid; s < T; s += BS) {
        int r = src[s] - 1;          // inclusive prefix minus self
        if (r >= 1) {
            float kf  = (float)(s + 1);
            float km  = (float)s;
            float ri  = __fdiv_rn(kf, 800.0f);
            float rim = __fdiv_rn(km, 800.0f);
            float pi  = __fdiv_rn(kf, (float)(r + 1));
            float pim = __fdiv_rn(km, (float)r);
            sum = __fadd_rn(sum,
                  __fmul_rn(__fmul_rn(__fsub_rn(ri, rim), __fadd_rn(pi, pim)), 0.5f));
        }
    }
    red[tid] = sum;
    __syncthreads();
    for (int s2 = BS / 2; s2 > 0; s2 >>= 1) {
        if (tid < s2) red[tid] = __fadd_rn(red[tid], red[tid + s2]);
        __syncthreads();
    }
    if (tid == 0) ap[c] = red[0];
}

// ---------------- mean over classes ----------------
__global__ void mean_kernel(const float* __restrict__ ap, float* __restrict__ out) {
    if (threadIdx.x == 0) {
        float s = 0.0f;
        for (int c = 0; c < C; ++c) s = __fadd_rn(s, ap[c]);
        out[0] = __fdiv_rn(s, 80.0f);
    }
}

extern "C" void kernel_launch(void* const* d_in, const int* in_sizes, int n_in,
                              void* d_out, int out_size, void* d_ws, size_t ws_size,
                              hipStream_t stream) {
    const float* pred = (const float*)d_in[0];   // [C, P, 7] f32
    const float* gt   = (const float*)d_in[1];   // [C, G, 7] f32
    float* out = (float*)d_out;

    // Workspace layout — 12,585,984 B total (was 24.7 MB): the pred-side
    // scatter plumbing (predCnt/predOff/predCur/predP/cellB) is gone; match3
    // streams preds in original order. Re-poisoned 0xAA each call — gt_bin
    // (incl. folded init) / match3 / sortc rewrite everything
    // read-before-write.
    char* ws = (char*)d_ws;
    int*                sortT      = (int*)               (ws + 0);         //     320 B
    float*              ap         = (float*)             (ws + 512);       //     320 B
    unsigned short*     gtCnt      = (unsigned short*)    (ws + 1024);      //  40960 B
    unsigned short*     gtOff      = (unsigned short*)    (ws + 41984);     //  40960 B
    unsigned short*     gtIdx      = (unsigned short*)    (ws + 82944);     // 128000 B
    float*              gtAbe      = (float*)             (ws + 210944);    // 256000 B
    float4*             gtBox      = (float4*)            (ws + 466944);    // 1.024 MB (16-aligned)
    unsigned long long* gtKey      = (unsigned long long*)(ws + 1490944);   // 512000 B
    unsigned long long* sortedKeys = (unsigned long long*)(ws + 2002944);   // 655360 B
    int*                gHist      = (int*)               (ws + 2658304);   // 327680 B
    float*              scoreC     = (float*)             (ws + 2985984);   // 9.6 MB
    // end: 12585984 B

    const int M_BLK = (P + BS * PPT - 1) / (BS * PPT);   // 59

    gt_bin_kernel<<<C, BS, 0, stream>>>(gt, gtCnt, gtOff, gtBox, gtAbe, gtIdx, gtKey, gHist);
    match3_kernel<<<dim3(M_BLK, C), BS, 0, stream>>>(pred, gtOff, gtCnt, gtBox, gtAbe, gtIdx,
                                                     scoreC, gtKey);
    sortc_kernel<<<C, BS, 0, stream>>>(gtKey, sortedKeys, sortT);
    hist_kernel<<<dim3(HCH, C), BS, 0, stream>>>(scoreC, sortedKeys, gHist);
    ap2_kernel<<<C, BS, 0, stream>>>(sortT, gHist, ap);
    mean_kernel<<<1, 64, 0, stream>>>(ap, out);
}